// Round 10
// baseline (387.644 us; speedup 1.0000x reference)
//
#include <hip/hip_runtime.h>
#include <cstdint>
#include <cstddef>

// ============================================================================
// SSD forward (image 7 only) + NMS, all fp32.
// R24: base = R19 (best 357.3us; R23's unroll-4 was neutral -> back to 2).
// conv3 ledger closed: weight-path x3 invariant, KSPLIT forbidden (R22:
// conv3 split alone reproduces R15's exact 0.5097 fail), reg-dbuf spills,
// unroll neutral. conv3 = 83us @ 16 waves/CU is the structure floor.
// NEW LEVER: conv2 runs COPT=8 -> only 16 waves/CU. Precedent: conv3's
// 8->4 scan was -13% (113->98, old structure) — wave doubling won. conv2
// COPT 8->4: grid 1024->2048 blocks, 21KB LDS -> 7 blk/CU = 28 waves/CU
// (1.75x). BIT-EXACT: per-output fmaf chain (st,ci,tap asc) unchanged —
// COPT only remaps lanes to co. Cost: h1 staged 2x (+17MB L2/L3, trivial
// at conv2's 250GB/s). launch_bounds(256,8) caps VGPR<=64 (measured 52).
// Also: k_repack_all fused into k_conv1 (independent work, one launch,
// per-thread math identical) — saves a launch gap.
// ============================================================================

// ---------------- fused: weight repack (blocks 0..3968) + conv1 (rest) -------
__global__ __launch_bounds__(256) void k_pre(
    const float* __restrict__ x, const float* __restrict__ w1,
    const float* __restrict__ b1, float* __restrict__ h1,
    const float* __restrict__ w2, const float* __restrict__ w3,
    const float* __restrict__ w4, const float* __restrict__ regw,
    const float* __restrict__ clsw, float* __restrict__ wr2,
    float* __restrict__ wr3, float* __restrict__ wr4, float* __restrict__ wh) {
  __shared__ float in_t[3][33][33];
  if (blockIdx.x < 3969) {  // ---- repack (exact R19 k_repack_all body) ----
    int idx = blockIdx.x * 256 + threadIdx.x;
    if (idx < 73728) {  // conv2: CIN=64 COUT=128
      int co = idx % 128, r = idx / 128, ci = r / 9, tap = r % 9;
      wr2[idx] = w2[(co * 64 + ci) * 9 + tap];
    } else if (idx < 73728 + 294912) {  // conv3: CIN=128 COUT=256
      int i = idx - 73728;
      int co = i % 256, r = i / 256, ci = r / 9, tap = r % 9;
      wr3[i] = w3[(co * 128 + ci) * 9 + tap];
    } else if (idx < 73728 + 294912 + 589824) {  // conv4: CIN=256 COUT=256
      int i = idx - (73728 + 294912);
      int co = i % 256, r = i / 256, ci = r / 9, tap = r % 9;
      wr4[i] = w4[(co * 256 + ci) * 9 + tap];
    } else if (idx < 73728 + 294912 + 589824 + 57600) {  // head
      int i = idx - (73728 + 294912 + 589824);
      int ci = i & 255, r = i >> 8, tap = r / 25, o = r % 25;
      wh[i] = (o < 4) ? regw[(o * 256 + ci) * 9 + tap]
                      : clsw[((o - 4) * 256 + ci) * 9 + tap];
    }
    return;
  }
  // ---- conv1: 3->64, 512->256, stride 2 (exact R19 body, flat indexing) ----
  const int b = blockIdx.x - 3969;          // 0..2047
  const int tid = threadIdx.x;
  const int tx = tid & 15, ty = tid >> 4;
  const int ox0 = (b & 15) * 16, oy0 = ((b >> 4) & 15) * 16;
  const int co0 = (b >> 8) * 8;
  for (int idx = tid; idx < 3 * 33 * 33; idx += 256) {
    int ci = idx / 1089, rem = idx % 1089;
    int r = rem / 33, c = rem % 33;
    int iy = oy0 * 2 + r, ix = ox0 * 2 + c;
    float v = 0.f;
    if (iy < 512 && ix < 512) v = x[(size_t)ci * 262144 + iy * 512 + ix];
    in_t[ci][r][c] = v;
  }
  __syncthreads();
  float rin[27];
#pragma unroll
  for (int ci = 0; ci < 3; ++ci)
#pragma unroll
    for (int kh = 0; kh < 3; ++kh)
#pragma unroll
      for (int kw = 0; kw < 3; ++kw)
        rin[ci * 9 + kh * 3 + kw] = in_t[ci][2 * ty + kh][2 * tx + kw];
  const int oy = oy0 + ty, ox = ox0 + tx;
  for (int co = co0; co < co0 + 8; ++co) {  // co uniform -> weights via s_load
    float a = 0.f;
#pragma unroll
    for (int k = 0; k < 27; ++k) a = fmaf(w1[co * 27 + k], rin[k], a);
    h1[(size_t)co * 65536 + oy * 256 + ox] = fmaxf(a + b1[co], 0.f);
  }
}

// ---------------- generic stride-2 3x3 conv, SAME(pad lo 0 hi 1) -------------
// NW waves = NW co-groups (wave-uniform cout) x 64 lanes.
// Lane lp -> output position (py=lp/SW, px=lp%SW); SH*SW == 64.
// Input LDS row: [EV: SW+1 even cols | OD: SW odd cols | pad] = ROWW words.
// WLDS=1: weights double-buffered in LDS via global_load_lds (no VGPRs);
//         compute reads wave-uniform ds_read_b128 broadcast.
// WLDS=0: weights via wave-uniform s_load from global.
// MINW: min waves/EU for launch_bounds (8 caps VGPR at 64 for high occ).
// Per-output accumulation order: tap 0..8 = (kh,kw) lexicographic, ci asc
// — bit-identical to R12 in all paths (COPT/NW only remap lanes to co).
template <int CIN, int COUT, int HIN, int WIN, int SH, int SW, int COPT,
          int CIT, int KSPLIT, int ROWW, int NW, int WLDS, int MINW>
__global__ __launch_bounds__(NW * 64, MINW) void conv_s2(
    const float* __restrict__ in, const float* __restrict__ wr,
    const float* __restrict__ bias, float* __restrict__ out) {
  constexpr int HOUT = HIN / 2, WOUT = WIN / 2;
  constexpr int IH = SH * 2 + 1, IW = SW * 2 + 1;
  constexpr int EVW = SW + 1;
  constexpr int COT = NW * COPT;
  constexpr int NPAIR = CIT * IH * EVW;
  constexpr int NTHR = NW * 64;
  constexpr int NLD = (NPAIR + NTHR - 1) / NTHR;
  constexpr int NC4 = COPT / 4;          // float4 chunks per wave per tap
  constexpr int CO4 = COT / 4;           // float4 cols per weight slab row
  constexpr int W4  = CIT * 9 * CO4;     // float4s in per-stage weight slab
  static_assert(SH * SW == 64, "one position per lane");
  static_assert(EVW + SW < ROWW + 1, "pad slot fits");
  static_assert(COPT % 4 == 0, "float4 weight chunks");
  static_assert(!WLDS || (W4 % 64 == 0), "whole lane-rounds");
  __shared__ float lds[CIT * IH * ROWW];
  __shared__ float4 wlds4[WLDS == 1 ? 2 * W4 : (WLDS ? W4 : 1)];

  const int tid = threadIdx.x;
  const int gu  = __builtin_amdgcn_readfirstlane(tid >> 6);
  const int lp  = tid & 63;
  const int py  = lp / SW, px = lp % SW;

  constexpr int ntx = WOUT / SW;
  const int bx = blockIdx.x % ntx, by = blockIdx.x / ntx;
  const int ox0 = bx * SW, oy0 = by * SH;
  const int co_blk = blockIdx.y * COT;
  const int cobase = co_blk + gu * COPT;
  const int ci_begin = (KSPLIT > 1) ? blockIdx.z * (CIN / KSPLIT) : 0;
  constexpr int NST = (CIN / KSPLIT) / CIT;

  // ---- weight slab loader: global -> LDS direct, no VGPR round-trip ----
  auto wload = [&](int cibN, int bsel) {
#pragma unroll
    for (int r = 0; r < W4 / 64; ++r) {
      if ((r & (NW - 1)) == gu) {          // wave-uniform round split
        int f4 = r * 64 + lp;
        int row = f4 / CO4, c4 = f4 % CO4; // row = ci*9+tap within stage
        const float* g =
            wr + (size_t)(cibN * 9 + row) * COUT + co_blk + c4 * 4;
        __builtin_amdgcn_global_load_lds(
            (const __attribute__((address_space(1))) void*)g,
            (__attribute__((address_space(3))) void*)&wlds4[bsel * W4 + r * 64],
            16, 0, 0);
      }
    }
  };

  // ---- stage-invariant INPUT staging descriptors (advance by channel) ----
  unsigned goff[NLD];  // float offset of even element
  int      loff[NLD];  // LDS even-slot word offset; -1 if idx >= NPAIR
  int      mode[NLD];  // 0 = zero-fill, 1 = float2 pair, 2 = single even col
#pragma unroll
  for (int j = 0; j < NLD; ++j) {
    int idx = tid + j * NTHR;
    bool act = (idx < NPAIR);
    int ci = idx / (IH * EVW), rem = idx % (IH * EVW);
    int r = rem / EVW, c2 = rem % EVW;
    int iy = oy0 * 2 + r, ix = ox0 * 2 + 2 * c2;
    loff[j] = act ? (ci * IH + r) * ROWW + c2 : -1;
    goff[j] = (unsigned)((ci_begin + ci) * HIN * WIN + iy * WIN + ix);
    int m = 0;
    if (act && iy < HIN) {
      if ((2 * c2 + 1 < IW) && (ix + 1 < WIN)) m = 1;
      else if (ix < WIN) m = 2;
    }
    mode[j] = m;
  }

  // ---- prologue: issue stage-0 weight slab + prefetch stage-0 inputs ----
  if constexpr (WLDS) wload(ci_begin, 0);
  float2 pre[NLD];
#pragma unroll
  for (int j = 0; j < NLD; ++j) {
    float2 t = make_float2(0.f, 0.f);
    if (mode[j] == 1)      t = *(const float2*)(in + goff[j]);
    else if (mode[j] == 2) t.x = in[goff[j]];
    pre[j] = t;
  }

  float acc[COPT] = {};

  constexpr unsigned IADV = (unsigned)(CIT * HIN * WIN);
  unsigned iadv = IADV;
  for (int st = 0; st < NST; ++st, iadv += IADV) {
    const int cib = ci_begin + st * CIT;
    if (st) {
      __syncthreads();   // previous stage's compute reads done (slab free)
      if constexpr (WLDS == 2) wload(cib, 0);  // single-buffer slab load
    }
    // ---- write prefetched stage st inputs to LDS (same slots as R12) ----
#pragma unroll
    for (int j = 0; j < NLD; ++j) {
      if (loff[j] >= 0) {
        lds[loff[j]] = pre[j].x;        // even col c2
        lds[loff[j] + EVW] = pre[j].y;  // odd col c2 (c2==SW -> pad slot)
      }
    }
    __syncthreads();  // hipcc drains vmcnt(0) here -> weight slab st ready
    // ---- issue stage st+1's loads AFTER the barrier: drained at the NEXT
    //      stage's barriers, i.e. hidden under the compute phase below ----
    if (st + 1 < NST) {
      if constexpr (WLDS == 1) wload(cib + CIT, (st + 1) & 1);
#pragma unroll
      for (int j = 0; j < NLD; ++j) {
        float2 t = make_float2(0.f, 0.f);
        if (mode[j] == 1)      t = *(const float2*)(in + goff[j] + iadv);
        else if (mode[j] == 2) t.x = in[goff[j] + iadv];
        pre[j] = t;
      }
    }
    // ---- compute: 9 taps per ci; inputs from LDS; weights per WLDS ----
#pragma unroll 2
    for (int ci = 0; ci < CIT; ++ci) {
      const int b0 = (ci * IH + 2 * py) * ROWW + px;
      float in9[9];
      in9[0] = lds[b0];                    // (kh0,kw0) col 2px
      in9[1] = lds[b0 + EVW];              // (kh0,kw1) col 2px+1
      in9[2] = lds[b0 + 1];                // (kh0,kw2) col 2px+2
      in9[3] = lds[b0 + ROWW];
      in9[4] = lds[b0 + ROWW + EVW];
      in9[5] = lds[b0 + ROWW + 1];
      in9[6] = lds[b0 + 2 * ROWW];
      in9[7] = lds[b0 + 2 * ROWW + EVW];
      in9[8] = lds[b0 + 2 * ROWW + 1];
      if constexpr (WLDS) {
        const float4* wb = (WLDS == 1) ? &wlds4[(st & 1) * W4] : &wlds4[0];
        const int wrow = ci * 9 * CO4 + gu * NC4;
#pragma unroll
        for (int t = 0; t < 9; ++t) {
#pragma unroll
          for (int q = 0; q < NC4; ++q) {
            float4 wv = wb[wrow + t * CO4 + q];
            acc[q * 4 + 0] = fmaf(in9[t], wv.x, acc[q * 4 + 0]);
            acc[q * 4 + 1] = fmaf(in9[t], wv.y, acc[q * 4 + 1]);
            acc[q * 4 + 2] = fmaf(in9[t], wv.z, acc[q * 4 + 2]);
            acc[q * 4 + 3] = fmaf(in9[t], wv.w, acc[q * 4 + 3]);
          }
        }
      } else {
        const float* wp = wr + (size_t)(cib + ci) * 9 * COUT + cobase;
#pragma unroll
        for (int t = 0; t < 9; ++t)
#pragma unroll
          for (int c = 0; c < COPT; ++c)
            acc[c] = fmaf(in9[t], wp[t * COUT + c], acc[c]);
      }
    }
  }

  const int oy = oy0 + py, ox = ox0 + px;
#pragma unroll
  for (int c = 0; c < COPT; ++c) {
    int co = cobase + c;
    if constexpr (KSPLIT > 1) {
      out[((size_t)blockIdx.z * COUT + co) * (HOUT * WOUT) + oy * WOUT + ox] =
          acc[c];
    } else {
      out[(size_t)co * (HOUT * WOUT) + oy * WOUT + ox] =
          fmaxf(acc[c] + bias[co], 0.f);
    }
  }
}

// ---------------- combine conv4 K-split partials + bias + relu, write NHWC ---
// EXACT R0 semantics: v = ((p0+p1)+p2)+p3; out = max(v+b, 0)
__global__ __launch_bounds__(256) void k_combine(const float* __restrict__ part,
                                                 const float* __restrict__ b,
                                                 float* __restrict__ h4t) {
  int co = blockIdx.x;  // 0..255
  float bb = b[co];
  for (int k2 = 0; k2 < 4; ++k2) {
    int pos = threadIdx.x + k2 * 256;
    float v = part[(size_t)(0 * 256 + co) * 1024 + pos] +
              part[(size_t)(1 * 256 + co) * 1024 + pos] +
              part[(size_t)(2 * 256 + co) * 1024 + pos] +
              part[(size_t)(3 * 256 + co) * 1024 + pos];
    h4t[(size_t)pos * 256 + co] = fmaxf(v + bb, 0.f);
  }
}

// ---------------- head: reg(4)+cls(21) stride-1 conv + softmax/max/argmax ----
__global__ __launch_bounds__(256) void k_head(const float* __restrict__ h4t,
                                              const float* __restrict__ wh,
                                              const float* __restrict__ regb,
                                              const float* __restrict__ clsb,
                                              float* __restrict__ locs,
                                              float* __restrict__ confs,
                                              float* __restrict__ scores,
                                              float* __restrict__ labelsF) {
  const int pos = blockIdx.x;
  const int py = pos >> 5, px = pos & 31;
  const int t = threadIdx.x;
  float part[25] = {};
#pragma unroll
  for (int kh = 0; kh < 3; ++kh) {
    int iy = py + kh - 1;
    if (iy < 0 || iy > 31) continue;  // block-uniform
#pragma unroll
    for (int kw = 0; kw < 3; ++kw) {
      int ix = px + kw - 1;
      if (ix < 0 || ix > 31) continue;
      int tap = kh * 3 + kw;
      float v = h4t[(size_t)(iy * 32 + ix) * 256 + t];
      const float* wp = wh + (size_t)tap * 25 * 256 + t;
#pragma unroll
      for (int o = 0; o < 25; ++o)
        part[o] = fmaf(v, wp[(size_t)o * 256], part[o]);
    }
  }
#pragma unroll
  for (int o = 0; o < 25; ++o) {
#pragma unroll
    for (int d = 1; d < 64; d <<= 1) part[o] += __shfl_xor(part[o], d);
  }
  __shared__ float red[4][25];
  __shared__ float yv[25];
  const int wv = t >> 6, ln = t & 63;
  if (ln == 0) {
#pragma unroll
    for (int o = 0; o < 25; ++o) red[wv][o] = part[o];
  }
  __syncthreads();
  if (t < 25) {
    float y = red[0][t] + red[1][t] + red[2][t] + red[3][t];
    y += (t < 4) ? regb[t] : clsb[t - 4];
    if (t < 4) locs[(size_t)pos * 4 + t] = y;
    else       confs[(size_t)pos * 21 + (t - 4)] = y;
    yv[t] = y;
  }
  __syncthreads();
  if (t == 0) {
    float m = yv[4];
    int lab = 0;
    for (int j = 1; j < 21; ++j)
      if (yv[4 + j] > m) { m = yv[4 + j]; lab = j; }  // first-max semantics
    float s = 0.f;
    for (int j = 0; j < 21; ++j) s += expf(yv[4 + j] - m);
    scores[pos] = 1.f / s;   // max softmax prob
    labelsF[pos] = (float)lab;
  }
}

// ---------------- stable descending bitonic sort of 1024 scores --------------
__global__ __launch_bounds__(512) void k_sort(const float* __restrict__ scores,
                                              const float* __restrict__ locs,
                                              int* __restrict__ order,
                                              float* __restrict__ ssc,
                                              float* __restrict__ bsrt,
                                              unsigned long long* __restrict__ vbits) {
  __shared__ float sk[1024];
  __shared__ int   si[1024];
  const int t = threadIdx.x;
  sk[t] = scores[t];           si[t] = t;
  sk[t + 512] = scores[t + 512]; si[t + 512] = t + 512;
  for (int k = 2; k <= 1024; k <<= 1) {
    for (int j = k >> 1; j > 0; j >>= 1) {
      __syncthreads();
      int i1 = ((t / j) * (2 * j)) + (t % j);
      int i2 = i1 + j;
      bool up = (i1 & k) == 0;
      float sa = sk[i1], sb = sk[i2];
      int ia = si[i1], ib = si[i2];
      bool b_before_a = (sb > sa) || (sb == sa && ib < ia);
      bool a_before_b = (sa > sb) || (sa == sb && ia < ib);
      bool sw = up ? b_before_a : a_before_b;
      if (sw) { sk[i1] = sb; sk[i2] = sa; si[i1] = ib; si[i2] = ia; }
    }
  }
  __syncthreads();
  for (int i = t; i < 1024; i += 512) {
    int oi = si[i];
    order[i] = oi;
    ssc[i] = sk[i];
    ((float4*)bsrt)[i] = ((const float4*)locs)[oi];
  }
  if (t < 16) {  // validity bits (score > SCORE_THR), sorted order
    unsigned long long w = 0;
    for (int b2 = 0; b2 < 64; ++b2)
      if (sk[t * 64 + b2] > 0.04f) w |= (1ull << b2);
    vbits[t] = w;
  }
}

// ---------------- pairwise IoU suppression bitmask (1024x1024 bits) ----------
__global__ __launch_bounds__(256) void k_mask(const float* __restrict__ bsrt,
                                              unsigned long long* __restrict__ mask) {
  __shared__ float4 sb[1024];
  const int t = threadIdx.x;
  for (int idx = t; idx < 1024; idx += 256)
    sb[idx] = ((const float4*)bsrt)[idx];
  __syncthreads();
  const int i = blockIdx.x * 16 + (t & 15);
  const int w = t >> 4;
  float4 bi = sb[i];
  float ai = (bi.z - bi.x) * (bi.w - bi.y);
  unsigned long long bits = 0;
  for (int jj = 0; jj < 64; ++jj) {
    float4 bj = sb[w * 64 + jj];
    float aj = (bj.z - bj.x) * (bj.w - bj.y);
    float ltx = fmaxf(bi.x, bj.x), lty = fmaxf(bi.y, bj.y);
    float rbx = fminf(bi.z, bj.z), rby = fminf(bi.w, bj.w);
    float inter = fmaxf(rbx - ltx, 0.f) * fmaxf(rby - lty, 0.f);
    float uni = ai + aj - inter;
    float iou = inter / (uni + 1e-9f);
    if (iou > 0.5f) bits |= (1ull << jj);
  }
  mask[(size_t)i * 16 + w] = bits;
}

// ---------------- parallel fixpoint greedy NMS + fused gather ----------------
__global__ __launch_bounds__(1024) void k_nms_gather(
    const unsigned long long* __restrict__ mask,
    const unsigned long long* __restrict__ vbits,
    const int* __restrict__ order, const float* __restrict__ ssc,
    const float* __restrict__ locs, const float* __restrict__ confs,
    const float* __restrict__ labelsF, float* __restrict__ out) {
  __shared__ unsigned long long KEEP[16], DEAD[16];
  __shared__ int ncert;
  const int i = threadIdx.x;        // box index (sorted order)
  const int w = i >> 6, l = i & 63; // wave, lane

  unsigned long long R[16];
#pragma unroll
  for (int k = 0; k < 16; ++k) {
    unsigned long long m = 0;
    if (k < w) m = mask[(size_t)i * 16 + k];
    else if (k == w && l) m = mask[(size_t)i * 16 + k] & ((1ull << l) - 1ull);
    R[k] = m;
  }
  const bool valid = (vbits[w] >> l) & 1ull;

  if (i < 16) { KEEP[i] = 0ull; DEAD[i] = 0ull; }
  if (i == 0) ncert = 0;
  __syncthreads();

  int status = 0;  // 0 unknown, 1 kept, 2 dead
  for (;;) {
    unsigned long long s = 0, p = 0;
    if (status == 0) {
#pragma unroll
      for (int k = 0; k < 16; ++k) {
        unsigned long long K_ = KEEP[k], D_ = DEAD[k];
        s |= R[k] & K_;
        p |= R[k] & ~D_;
      }
    }
    __syncthreads();  // all reads done before any write
    bool newKeep = false, newDead = false;
    if (status == 0) {
      if (!valid)      { status = 2; newDead = true; }
      else if (s)      { status = 2; newDead = true; }
      else if (!p)     { status = 1; newKeep = true; }
    }
    unsigned long long bk = __ballot(newKeep);
    unsigned long long bd = __ballot(newDead);
    if (l == 0) {
      if (bk) KEEP[w] |= bk;
      if (bd) DEAD[w] |= bd;
      int n = __popcll(bk) + __popcll(bd);
      if (n) atomicAdd(&ncert, n);
    }
    __syncthreads();
    if (ncert >= 1024) break;
  }

  const bool kp = (status == 1);
  const int oi = order[i];
  float4 bx = kp ? ((const float4*)locs)[oi]
                 : make_float4(-1.f, -1.f, -1.f, -1.f);
  ((float4*)out)[i] = bx;
  out[4096 + i] = kp ? labelsF[oi] : 0.f;
  out[5120 + i] = kp ? ssc[i] : -1.f;
  float* oc = out + 6144 + (size_t)i * 21;
  const float* cc = confs + (size_t)oi * 21;
#pragma unroll
  for (int c = 0; c < 21; ++c) oc[c] = kp ? cc[c] : -1.f;
}

// ============================================================================
extern "C" void kernel_launch(void* const* d_in, const int* in_sizes, int n_in,
                              void* d_out, int out_size, void* d_ws, size_t ws_size,
                              hipStream_t stream) {
  const float* x    = (const float*)d_in[0] + (size_t)7 * 3 * 512 * 512;  // image 7
  const float* w1   = (const float*)d_in[1];
  const float* b1   = (const float*)d_in[2];
  const float* w2   = (const float*)d_in[3];
  const float* b2   = (const float*)d_in[4];
  const float* w3   = (const float*)d_in[5];
  const float* b3   = (const float*)d_in[6];
  const float* w4   = (const float*)d_in[7];
  const float* b4   = (const float*)d_in[8];
  const float* regw = (const float*)d_in[9];
  const float* regb = (const float*)d_in[10];
  const float* clsw = (const float*)d_in[11];
  const float* clsb = (const float*)d_in[12];
  float* out = (float*)d_out;
  char* ws = (char*)d_ws;

  // region A (0..16.8MB): h1, then part4 + h4t   (R12 layout)
  float* h1    = (float*)(ws + 0);          // 16.8MB  (dead after conv2)
  float* part4 = (float*)(ws + 0);          // 4MB     (dead after combine)
  float* h4t   = (float*)(ws + 9437184);    // 1MB
  float* h2    = (float*)(ws + 16777216);   // 8.4MB   (dead after conv3)
  float* h3    = (float*)(ws + 25165824);   // 4.2MB
  float* wr2   = (float*)(ws + 29360128);
  float* wr3   = (float*)(ws + 29655040);
  float* wr4   = (float*)(ws + 30834688);
  float* wh    = (float*)(ws + 33193984);
  float* locs  = (float*)(ws + 33424384);
  float* confs = (float*)(ws + 33440768);
  float* scores  = (float*)(ws + 33526784);
  float* labelsF = (float*)(ws + 33530880);
  int*   order   = (int*)  (ws + 33534976);
  float* ssc     = (float*)(ws + 33539072);
  float* bsrt    = (float*)(ws + 33543168);
  unsigned long long* mask  = (unsigned long long*)(ws + 33559552);
  unsigned long long* vbits = (unsigned long long*)(ws + 33690624);

  // fused repack (3969 blocks) + conv1 (2048 blocks)
  k_pre<<<6017, 256, 0, stream>>>(x, w1, b1, h1, w2, w3, w4, regw, clsw,
                                  wr2, wr3, wr4, wh);

  // conv2: COPT=4 (was 8) -> 256 sp x 8 co = 2048 blocks, 28 waves/CU.
  // s_load path, ROWW=36, launch_bounds MINW=8 caps VGPR<=64. Bit-exact.
  conv_s2<64, 128, 256, 256, 4, 16, 4, 16, 1, 36, 4, 0, 8>
      <<<dim3(256, 8, 1), 256, 0, stream>>>(h1, wr2, b2, h2);
  // conv3: COPT=4, 1024 blocks, ROWW=20, weight-LDS dbuf (R19)
  conv_s2<128, 256, 128, 128, 8, 8, 4, 16, 1, 20, 4, 1, 4>
      <<<dim3(64, 16, 1), 256, 0, stream>>>(h2, wr3, b3, h3);
  // conv4: COPT=4, KSPLIT=4, 1024 blocks, weight-LDS dbuf (R19)
  conv_s2<256, 256, 64, 64, 8, 8, 4, 16, 4, 20, 4, 1, 4>
      <<<dim3(16, 16, 4), 256, 0, stream>>>(h3, wr4, (const float*)nullptr, part4);
  k_combine<<<256, 256, 0, stream>>>(part4, b4, h4t);

  k_head<<<1024, 256, 0, stream>>>(h4t, wh, regb, clsb, locs, confs, scores, labelsF);

  k_sort<<<1, 512, 0, stream>>>(scores, locs, order, ssc, bsrt, vbits);
  k_mask<<<64, 256, 0, stream>>>(bsrt, mask);
  k_nms_gather<<<1, 1024, 0, stream>>>(mask, vbits, order, ssc, locs, confs,
                                       labelsF, out);
}

// Round 11
// 358.020 us; speedup vs baseline: 1.0827x; 1.0827x over previous
//
#include <hip/hip_runtime.h>
#include <cstdint>
#include <cstddef>

// ============================================================================
// SSD forward (image 7 only) + NMS, all fp32.
// R25: revert to R19 (verified best 357.3us) + keep R24's k_pre fusion only.
// R24 post-mortem: conv2 COPT=4 regressed (occupancy did NOT rise — 42.6%,
// same ~4 blk/CU despite LDS/VGPR permitting 7; FETCH 2x; conflicts 10x).
// Across R12-R24, conv_s2 VALUBusy is pinned 31-36% under every variant
// (weight path x3, occupancy, unroll, COPT) -> the barrier-phased issue
// structure is the invariant bottleneck, and the bit-exact accumulation
// constraint (R22: conv3 split alone reproduces R15's 0.5097 fail) forbids
// the restructures that would change it.
// CLOSED LEDGER (conv_s2): weight path invariant; KSPLIT forbidden;
// reg-dbuf spills (R17/R21); unroll neutral (R23); COPT scans complete
// (conv3 8/4/2 = 113/98/120; conv2 4 = 84 > 8). conv3 ~83us is the floor.
// Config: conv2 COPT=8 WLDS=0; conv3 COPT=4 WLDS=1; conv4 KSPLIT=4 WLDS=1;
// k_pre = fused repack+conv1 (R24, numerics-passed, per-thread math exact).
// ============================================================================

// ---------------- fused: weight repack (blocks 0..3968) + conv1 (rest) -------
__global__ __launch_bounds__(256) void k_pre(
    const float* __restrict__ x, const float* __restrict__ w1,
    const float* __restrict__ b1, float* __restrict__ h1,
    const float* __restrict__ w2, const float* __restrict__ w3,
    const float* __restrict__ w4, const float* __restrict__ regw,
    const float* __restrict__ clsw, float* __restrict__ wr2,
    float* __restrict__ wr3, float* __restrict__ wr4, float* __restrict__ wh) {
  __shared__ float in_t[3][33][33];
  if (blockIdx.x < 3969) {  // ---- repack (exact R19 k_repack_all body) ----
    int idx = blockIdx.x * 256 + threadIdx.x;
    if (idx < 73728) {  // conv2: CIN=64 COUT=128
      int co = idx % 128, r = idx / 128, ci = r / 9, tap = r % 9;
      wr2[idx] = w2[(co * 64 + ci) * 9 + tap];
    } else if (idx < 73728 + 294912) {  // conv3: CIN=128 COUT=256
      int i = idx - 73728;
      int co = i % 256, r = i / 256, ci = r / 9, tap = r % 9;
      wr3[i] = w3[(co * 128 + ci) * 9 + tap];
    } else if (idx < 73728 + 294912 + 589824) {  // conv4: CIN=256 COUT=256
      int i = idx - (73728 + 294912);
      int co = i % 256, r = i / 256, ci = r / 9, tap = r % 9;
      wr4[i] = w4[(co * 256 + ci) * 9 + tap];
    } else if (idx < 73728 + 294912 + 589824 + 57600) {  // head
      int i = idx - (73728 + 294912 + 589824);
      int ci = i & 255, r = i >> 8, tap = r / 25, o = r % 25;
      wh[i] = (o < 4) ? regw[(o * 256 + ci) * 9 + tap]
                      : clsw[((o - 4) * 256 + ci) * 9 + tap];
    }
    return;
  }
  // ---- conv1: 3->64, 512->256, stride 2 (exact R19 body, flat indexing) ----
  const int b = blockIdx.x - 3969;          // 0..2047
  const int tid = threadIdx.x;
  const int tx = tid & 15, ty = tid >> 4;
  const int ox0 = (b & 15) * 16, oy0 = ((b >> 4) & 15) * 16;
  const int co0 = (b >> 8) * 8;
  for (int idx = tid; idx < 3 * 33 * 33; idx += 256) {
    int ci = idx / 1089, rem = idx % 1089;
    int r = rem / 33, c = rem % 33;
    int iy = oy0 * 2 + r, ix = ox0 * 2 + c;
    float v = 0.f;
    if (iy < 512 && ix < 512) v = x[(size_t)ci * 262144 + iy * 512 + ix];
    in_t[ci][r][c] = v;
  }
  __syncthreads();
  float rin[27];
#pragma unroll
  for (int ci = 0; ci < 3; ++ci)
#pragma unroll
    for (int kh = 0; kh < 3; ++kh)
#pragma unroll
      for (int kw = 0; kw < 3; ++kw)
        rin[ci * 9 + kh * 3 + kw] = in_t[ci][2 * ty + kh][2 * tx + kw];
  const int oy = oy0 + ty, ox = ox0 + tx;
  for (int co = co0; co < co0 + 8; ++co) {  // co uniform -> weights via s_load
    float a = 0.f;
#pragma unroll
    for (int k = 0; k < 27; ++k) a = fmaf(w1[co * 27 + k], rin[k], a);
    h1[(size_t)co * 65536 + oy * 256 + ox] = fmaxf(a + b1[co], 0.f);
  }
}

// ---------------- generic stride-2 3x3 conv, SAME(pad lo 0 hi 1) -------------
// NW waves = NW co-groups (wave-uniform cout) x 64 lanes.
// Lane lp -> output position (py=lp/SW, px=lp%SW); SH*SW == 64.
// Input LDS row: [EV: SW+1 even cols | OD: SW odd cols | pad] = ROWW words.
// WLDS=1: weights double-buffered in LDS via global_load_lds (no VGPRs);
//         compute reads wave-uniform ds_read_b128 broadcast.
// WLDS=0: weights via wave-uniform s_load from global.
// Per-output accumulation order: tap 0..8 = (kh,kw) lexicographic, ci asc
// — bit-identical to R12 in all paths.
template <int CIN, int COUT, int HIN, int WIN, int SH, int SW, int COPT,
          int CIT, int KSPLIT, int ROWW, int NW, int WLDS>
__global__ __launch_bounds__(NW * 64, 4) void conv_s2(
    const float* __restrict__ in, const float* __restrict__ wr,
    const float* __restrict__ bias, float* __restrict__ out) {
  constexpr int HOUT = HIN / 2, WOUT = WIN / 2;
  constexpr int IH = SH * 2 + 1, IW = SW * 2 + 1;
  constexpr int EVW = SW + 1;
  constexpr int COT = NW * COPT;
  constexpr int NPAIR = CIT * IH * EVW;
  constexpr int NTHR = NW * 64;
  constexpr int NLD = (NPAIR + NTHR - 1) / NTHR;
  constexpr int NC4 = COPT / 4;          // float4 chunks per wave per tap
  constexpr int CO4 = COT / 4;           // float4 cols per weight slab row
  constexpr int W4  = CIT * 9 * CO4;     // float4s in per-stage weight slab
  static_assert(SH * SW == 64, "one position per lane");
  static_assert(EVW + SW < ROWW + 1, "pad slot fits");
  static_assert(COPT % 4 == 0, "float4 weight chunks");
  static_assert(!WLDS || (W4 % 64 == 0), "whole lane-rounds");
  __shared__ float lds[CIT * IH * ROWW];
  __shared__ float4 wlds4[WLDS == 1 ? 2 * W4 : (WLDS ? W4 : 1)];

  const int tid = threadIdx.x;
  const int gu  = __builtin_amdgcn_readfirstlane(tid >> 6);
  const int lp  = tid & 63;
  const int py  = lp / SW, px = lp % SW;

  constexpr int ntx = WOUT / SW;
  const int bx = blockIdx.x % ntx, by = blockIdx.x / ntx;
  const int ox0 = bx * SW, oy0 = by * SH;
  const int co_blk = blockIdx.y * COT;
  const int cobase = co_blk + gu * COPT;
  const int ci_begin = (KSPLIT > 1) ? blockIdx.z * (CIN / KSPLIT) : 0;
  constexpr int NST = (CIN / KSPLIT) / CIT;

  // ---- weight slab loader: global -> LDS direct, no VGPR round-trip ----
  auto wload = [&](int cibN, int bsel) {
#pragma unroll
    for (int r = 0; r < W4 / 64; ++r) {
      if ((r & (NW - 1)) == gu) {          // wave-uniform round split
        int f4 = r * 64 + lp;
        int row = f4 / CO4, c4 = f4 % CO4; // row = ci*9+tap within stage
        const float* g =
            wr + (size_t)(cibN * 9 + row) * COUT + co_blk + c4 * 4;
        __builtin_amdgcn_global_load_lds(
            (const __attribute__((address_space(1))) void*)g,
            (__attribute__((address_space(3))) void*)&wlds4[bsel * W4 + r * 64],
            16, 0, 0);
      }
    }
  };

  // ---- stage-invariant INPUT staging descriptors (advance by channel) ----
  unsigned goff[NLD];  // float offset of even element
  int      loff[NLD];  // LDS even-slot word offset; -1 if idx >= NPAIR
  int      mode[NLD];  // 0 = zero-fill, 1 = float2 pair, 2 = single even col
#pragma unroll
  for (int j = 0; j < NLD; ++j) {
    int idx = tid + j * NTHR;
    bool act = (idx < NPAIR);
    int ci = idx / (IH * EVW), rem = idx % (IH * EVW);
    int r = rem / EVW, c2 = rem % EVW;
    int iy = oy0 * 2 + r, ix = ox0 * 2 + 2 * c2;
    loff[j] = act ? (ci * IH + r) * ROWW + c2 : -1;
    goff[j] = (unsigned)((ci_begin + ci) * HIN * WIN + iy * WIN + ix);
    int m = 0;
    if (act && iy < HIN) {
      if ((2 * c2 + 1 < IW) && (ix + 1 < WIN)) m = 1;
      else if (ix < WIN) m = 2;
    }
    mode[j] = m;
  }

  // ---- prologue: issue stage-0 weight slab + prefetch stage-0 inputs ----
  if constexpr (WLDS) wload(ci_begin, 0);
  float2 pre[NLD];
#pragma unroll
  for (int j = 0; j < NLD; ++j) {
    float2 t = make_float2(0.f, 0.f);
    if (mode[j] == 1)      t = *(const float2*)(in + goff[j]);
    else if (mode[j] == 2) t.x = in[goff[j]];
    pre[j] = t;
  }

  float acc[COPT] = {};

  constexpr unsigned IADV = (unsigned)(CIT * HIN * WIN);
  unsigned iadv = IADV;
  for (int st = 0; st < NST; ++st, iadv += IADV) {
    const int cib = ci_begin + st * CIT;
    if (st) {
      __syncthreads();   // previous stage's compute reads done (slab free)
      if constexpr (WLDS == 2) wload(cib, 0);  // single-buffer slab load
    }
    // ---- write prefetched stage st inputs to LDS (same slots as R12) ----
#pragma unroll
    for (int j = 0; j < NLD; ++j) {
      if (loff[j] >= 0) {
        lds[loff[j]] = pre[j].x;        // even col c2
        lds[loff[j] + EVW] = pre[j].y;  // odd col c2 (c2==SW -> pad slot)
      }
    }
    __syncthreads();  // hipcc drains vmcnt(0) here -> weight slab st ready
    // ---- issue stage st+1's loads AFTER the barrier: drained at the NEXT
    //      stage's barriers, i.e. hidden under the compute phase below ----
    if (st + 1 < NST) {
      if constexpr (WLDS == 1) wload(cib + CIT, (st + 1) & 1);
#pragma unroll
      for (int j = 0; j < NLD; ++j) {
        float2 t = make_float2(0.f, 0.f);
        if (mode[j] == 1)      t = *(const float2*)(in + goff[j] + iadv);
        else if (mode[j] == 2) t.x = in[goff[j] + iadv];
        pre[j] = t;
      }
    }
    // ---- compute: 9 taps per ci; inputs from LDS; weights per WLDS ----
#pragma unroll 2
    for (int ci = 0; ci < CIT; ++ci) {
      const int b0 = (ci * IH + 2 * py) * ROWW + px;
      float in9[9];
      in9[0] = lds[b0];                    // (kh0,kw0) col 2px
      in9[1] = lds[b0 + EVW];              // (kh0,kw1) col 2px+1
      in9[2] = lds[b0 + 1];                // (kh0,kw2) col 2px+2
      in9[3] = lds[b0 + ROWW];
      in9[4] = lds[b0 + ROWW + EVW];
      in9[5] = lds[b0 + ROWW + 1];
      in9[6] = lds[b0 + 2 * ROWW];
      in9[7] = lds[b0 + 2 * ROWW + EVW];
      in9[8] = lds[b0 + 2 * ROWW + 1];
      if constexpr (WLDS) {
        const float4* wb = (WLDS == 1) ? &wlds4[(st & 1) * W4] : &wlds4[0];
        const int wrow = ci * 9 * CO4 + gu * NC4;
#pragma unroll
        for (int t = 0; t < 9; ++t) {
#pragma unroll
          for (int q = 0; q < NC4; ++q) {
            float4 wv = wb[wrow + t * CO4 + q];
            acc[q * 4 + 0] = fmaf(in9[t], wv.x, acc[q * 4 + 0]);
            acc[q * 4 + 1] = fmaf(in9[t], wv.y, acc[q * 4 + 1]);
            acc[q * 4 + 2] = fmaf(in9[t], wv.z, acc[q * 4 + 2]);
            acc[q * 4 + 3] = fmaf(in9[t], wv.w, acc[q * 4 + 3]);
          }
        }
      } else {
        const float* wp = wr + (size_t)(cib + ci) * 9 * COUT + cobase;
#pragma unroll
        for (int t = 0; t < 9; ++t)
#pragma unroll
          for (int c = 0; c < COPT; ++c)
            acc[c] = fmaf(in9[t], wp[t * COUT + c], acc[c]);
      }
    }
  }

  const int oy = oy0 + py, ox = ox0 + px;
#pragma unroll
  for (int c = 0; c < COPT; ++c) {
    int co = cobase + c;
    if constexpr (KSPLIT > 1) {
      out[((size_t)blockIdx.z * COUT + co) * (HOUT * WOUT) + oy * WOUT + ox] =
          acc[c];
    } else {
      out[(size_t)co * (HOUT * WOUT) + oy * WOUT + ox] =
          fmaxf(acc[c] + bias[co], 0.f);
    }
  }
}

// ---------------- combine conv4 K-split partials + bias + relu, write NHWC ---
// EXACT R0 semantics: v = ((p0+p1)+p2)+p3; out = max(v+b, 0)
__global__ __launch_bounds__(256) void k_combine(const float* __restrict__ part,
                                                 const float* __restrict__ b,
                                                 float* __restrict__ h4t) {
  int co = blockIdx.x;  // 0..255
  float bb = b[co];
  for (int k2 = 0; k2 < 4; ++k2) {
    int pos = threadIdx.x + k2 * 256;
    float v = part[(size_t)(0 * 256 + co) * 1024 + pos] +
              part[(size_t)(1 * 256 + co) * 1024 + pos] +
              part[(size_t)(2 * 256 + co) * 1024 + pos] +
              part[(size_t)(3 * 256 + co) * 1024 + pos];
    h4t[(size_t)pos * 256 + co] = fmaxf(v + bb, 0.f);
  }
}

// ---------------- head: reg(4)+cls(21) stride-1 conv + softmax/max/argmax ----
__global__ __launch_bounds__(256) void k_head(const float* __restrict__ h4t,
                                              const float* __restrict__ wh,
                                              const float* __restrict__ regb,
                                              const float* __restrict__ clsb,
                                              float* __restrict__ locs,
                                              float* __restrict__ confs,
                                              float* __restrict__ scores,
                                              float* __restrict__ labelsF) {
  const int pos = blockIdx.x;
  const int py = pos >> 5, px = pos & 31;
  const int t = threadIdx.x;
  float part[25] = {};
#pragma unroll
  for (int kh = 0; kh < 3; ++kh) {
    int iy = py + kh - 1;
    if (iy < 0 || iy > 31) continue;  // block-uniform
#pragma unroll
    for (int kw = 0; kw < 3; ++kw) {
      int ix = px + kw - 1;
      if (ix < 0 || ix > 31) continue;
      int tap = kh * 3 + kw;
      float v = h4t[(size_t)(iy * 32 + ix) * 256 + t];
      const float* wp = wh + (size_t)tap * 25 * 256 + t;
#pragma unroll
      for (int o = 0; o < 25; ++o)
        part[o] = fmaf(v, wp[(size_t)o * 256], part[o]);
    }
  }
#pragma unroll
  for (int o = 0; o < 25; ++o) {
#pragma unroll
    for (int d = 1; d < 64; d <<= 1) part[o] += __shfl_xor(part[o], d);
  }
  __shared__ float red[4][25];
  __shared__ float yv[25];
  const int wv = t >> 6, ln = t & 63;
  if (ln == 0) {
#pragma unroll
    for (int o = 0; o < 25; ++o) red[wv][o] = part[o];
  }
  __syncthreads();
  if (t < 25) {
    float y = red[0][t] + red[1][t] + red[2][t] + red[3][t];
    y += (t < 4) ? regb[t] : clsb[t - 4];
    if (t < 4) locs[(size_t)pos * 4 + t] = y;
    else       confs[(size_t)pos * 21 + (t - 4)] = y;
    yv[t] = y;
  }
  __syncthreads();
  if (t == 0) {
    float m = yv[4];
    int lab = 0;
    for (int j = 1; j < 21; ++j)
      if (yv[4 + j] > m) { m = yv[4 + j]; lab = j; }  // first-max semantics
    float s = 0.f;
    for (int j = 0; j < 21; ++j) s += expf(yv[4 + j] - m);
    scores[pos] = 1.f / s;   // max softmax prob
    labelsF[pos] = (float)lab;
  }
}

// ---------------- stable descending bitonic sort of 1024 scores --------------
__global__ __launch_bounds__(512) void k_sort(const float* __restrict__ scores,
                                              const float* __restrict__ locs,
                                              int* __restrict__ order,
                                              float* __restrict__ ssc,
                                              float* __restrict__ bsrt,
                                              unsigned long long* __restrict__ vbits) {
  __shared__ float sk[1024];
  __shared__ int   si[1024];
  const int t = threadIdx.x;
  sk[t] = scores[t];           si[t] = t;
  sk[t + 512] = scores[t + 512]; si[t + 512] = t + 512;
  for (int k = 2; k <= 1024; k <<= 1) {
    for (int j = k >> 1; j > 0; j >>= 1) {
      __syncthreads();
      int i1 = ((t / j) * (2 * j)) + (t % j);
      int i2 = i1 + j;
      bool up = (i1 & k) == 0;
      float sa = sk[i1], sb = sk[i2];
      int ia = si[i1], ib = si[i2];
      bool b_before_a = (sb > sa) || (sb == sa && ib < ia);
      bool a_before_b = (sa > sb) || (sa == sb && ia < ib);
      bool sw = up ? b_before_a : a_before_b;
      if (sw) { sk[i1] = sb; sk[i2] = sa; si[i1] = ib; si[i2] = ia; }
    }
  }
  __syncthreads();
  for (int i = t; i < 1024; i += 512) {
    int oi = si[i];
    order[i] = oi;
    ssc[i] = sk[i];
    ((float4*)bsrt)[i] = ((const float4*)locs)[oi];
  }
  if (t < 16) {  // validity bits (score > SCORE_THR), sorted order
    unsigned long long w = 0;
    for (int b2 = 0; b2 < 64; ++b2)
      if (sk[t * 64 + b2] > 0.04f) w |= (1ull << b2);
    vbits[t] = w;
  }
}

// ---------------- pairwise IoU suppression bitmask (1024x1024 bits) ----------
__global__ __launch_bounds__(256) void k_mask(const float* __restrict__ bsrt,
                                              unsigned long long* __restrict__ mask) {
  __shared__ float4 sb[1024];
  const int t = threadIdx.x;
  for (int idx = t; idx < 1024; idx += 256)
    sb[idx] = ((const float4*)bsrt)[idx];
  __syncthreads();
  const int i = blockIdx.x * 16 + (t & 15);
  const int w = t >> 4;
  float4 bi = sb[i];
  float ai = (bi.z - bi.x) * (bi.w - bi.y);
  unsigned long long bits = 0;
  for (int jj = 0; jj < 64; ++jj) {
    float4 bj = sb[w * 64 + jj];
    float aj = (bj.z - bj.x) * (bj.w - bj.y);
    float ltx = fmaxf(bi.x, bj.x), lty = fmaxf(bi.y, bj.y);
    float rbx = fminf(bi.z, bj.z), rby = fminf(bi.w, bj.w);
    float inter = fmaxf(rbx - ltx, 0.f) * fmaxf(rby - lty, 0.f);
    float uni = ai + aj - inter;
    float iou = inter / (uni + 1e-9f);
    if (iou > 0.5f) bits |= (1ull << jj);
  }
  mask[(size_t)i * 16 + w] = bits;
}

// ---------------- parallel fixpoint greedy NMS + fused gather ----------------
__global__ __launch_bounds__(1024) void k_nms_gather(
    const unsigned long long* __restrict__ mask,
    const unsigned long long* __restrict__ vbits,
    const int* __restrict__ order, const float* __restrict__ ssc,
    const float* __restrict__ locs, const float* __restrict__ confs,
    const float* __restrict__ labelsF, float* __restrict__ out) {
  __shared__ unsigned long long KEEP[16], DEAD[16];
  __shared__ int ncert;
  const int i = threadIdx.x;        // box index (sorted order)
  const int w = i >> 6, l = i & 63; // wave, lane

  unsigned long long R[16];
#pragma unroll
  for (int k = 0; k < 16; ++k) {
    unsigned long long m = 0;
    if (k < w) m = mask[(size_t)i * 16 + k];
    else if (k == w && l) m = mask[(size_t)i * 16 + k] & ((1ull << l) - 1ull);
    R[k] = m;
  }
  const bool valid = (vbits[w] >> l) & 1ull;

  if (i < 16) { KEEP[i] = 0ull; DEAD[i] = 0ull; }
  if (i == 0) ncert = 0;
  __syncthreads();

  int status = 0;  // 0 unknown, 1 kept, 2 dead
  for (;;) {
    unsigned long long s = 0, p = 0;
    if (status == 0) {
#pragma unroll
      for (int k = 0; k < 16; ++k) {
        unsigned long long K_ = KEEP[k], D_ = DEAD[k];
        s |= R[k] & K_;
        p |= R[k] & ~D_;
      }
    }
    __syncthreads();  // all reads done before any write
    bool newKeep = false, newDead = false;
    if (status == 0) {
      if (!valid)      { status = 2; newDead = true; }
      else if (s)      { status = 2; newDead = true; }
      else if (!p)     { status = 1; newKeep = true; }
    }
    unsigned long long bk = __ballot(newKeep);
    unsigned long long bd = __ballot(newDead);
    if (l == 0) {
      if (bk) KEEP[w] |= bk;
      if (bd) DEAD[w] |= bd;
      int n = __popcll(bk) + __popcll(bd);
      if (n) atomicAdd(&ncert, n);
    }
    __syncthreads();
    if (ncert >= 1024) break;
  }

  const bool kp = (status == 1);
  const int oi = order[i];
  float4 bx = kp ? ((const float4*)locs)[oi]
                 : make_float4(-1.f, -1.f, -1.f, -1.f);
  ((float4*)out)[i] = bx;
  out[4096 + i] = kp ? labelsF[oi] : 0.f;
  out[5120 + i] = kp ? ssc[i] : -1.f;
  float* oc = out + 6144 + (size_t)i * 21;
  const float* cc = confs + (size_t)oi * 21;
#pragma unroll
  for (int c = 0; c < 21; ++c) oc[c] = kp ? cc[c] : -1.f;
}

// ============================================================================
extern "C" void kernel_launch(void* const* d_in, const int* in_sizes, int n_in,
                              void* d_out, int out_size, void* d_ws, size_t ws_size,
                              hipStream_t stream) {
  const float* x    = (const float*)d_in[0] + (size_t)7 * 3 * 512 * 512;  // image 7
  const float* w1   = (const float*)d_in[1];
  const float* b1   = (const float*)d_in[2];
  const float* w2   = (const float*)d_in[3];
  const float* b2   = (const float*)d_in[4];
  const float* w3   = (const float*)d_in[5];
  const float* b3   = (const float*)d_in[6];
  const float* w4   = (const float*)d_in[7];
  const float* b4   = (const float*)d_in[8];
  const float* regw = (const float*)d_in[9];
  const float* regb = (const float*)d_in[10];
  const float* clsw = (const float*)d_in[11];
  const float* clsb = (const float*)d_in[12];
  float* out = (float*)d_out;
  char* ws = (char*)d_ws;

  // region A (0..16.8MB): h1, then part4 + h4t   (R12 layout)
  float* h1    = (float*)(ws + 0);          // 16.8MB  (dead after conv2)
  float* part4 = (float*)(ws + 0);          // 4MB     (dead after combine)
  float* h4t   = (float*)(ws + 9437184);    // 1MB
  float* h2    = (float*)(ws + 16777216);   // 8.4MB   (dead after conv3)
  float* h3    = (float*)(ws + 25165824);   // 4.2MB
  float* wr2   = (float*)(ws + 29360128);
  float* wr3   = (float*)(ws + 29655040);
  float* wr4   = (float*)(ws + 30834688);
  float* wh    = (float*)(ws + 33193984);
  float* locs  = (float*)(ws + 33424384);
  float* confs = (float*)(ws + 33440768);
  float* scores  = (float*)(ws + 33526784);
  float* labelsF = (float*)(ws + 33530880);
  int*   order   = (int*)  (ws + 33534976);
  float* ssc     = (float*)(ws + 33539072);
  float* bsrt    = (float*)(ws + 33543168);
  unsigned long long* mask  = (unsigned long long*)(ws + 33559552);
  unsigned long long* vbits = (unsigned long long*)(ws + 33690624);

  // fused repack (3969 blocks) + conv1 (2048 blocks)
  k_pre<<<6017, 256, 0, stream>>>(x, w1, b1, h1, w2, w3, w4, regw, clsw,
                                  wr2, wr3, wr4, wh);

  // conv2: COPT=8, 256 sp x 4 co = 1024 blocks, ROWW=36, s_load path (R19)
  conv_s2<64, 128, 256, 256, 4, 16, 8, 16, 1, 36, 4, 0>
      <<<dim3(256, 4, 1), 256, 0, stream>>>(h1, wr2, b2, h2);
  // conv3: COPT=4, 64 sp x 16 co = 1024 blocks, ROWW=20, weight-LDS dbuf
  conv_s2<128, 256, 128, 128, 8, 8, 4, 16, 1, 20, 4, 1>
      <<<dim3(64, 16, 1), 256, 0, stream>>>(h2, wr3, b3, h3);
  // conv4: COPT=4, KSPLIT=4, 1024 blocks, weight-LDS dbuf (R19)
  conv_s2<256, 256, 64, 64, 8, 8, 4, 16, 4, 20, 4, 1>
      <<<dim3(16, 16, 4), 256, 0, stream>>>(h3, wr4, (const float*)nullptr, part4);
  k_combine<<<256, 256, 0, stream>>>(part4, b4, h4t);

  k_head<<<1024, 256, 0, stream>>>(h4t, wh, regb, clsb, locs, confs, scores, labelsF);

  k_sort<<<1, 512, 0, stream>>>(scores, locs, order, ssc, bsrt, vbits);
  k_mask<<<64, 256, 0, stream>>>(bsrt, mask);
  k_nms_gather<<<1, 1024, 0, stream>>>(mask, vbits, order, ssc, locs, confs,
                                       labelsF, out);
}

// Round 12
// 356.473 us; speedup vs baseline: 1.0874x; 1.0043x over previous
//
#include <hip/hip_runtime.h>
#include <cstdint>
#include <cstddef>

// ============================================================================
// SSD forward (image 7 only) + NMS, all fp32.
// R26: base = R25 (358.0us == R19-best within noise). conv_s2 ledger closed
// (weight path x3 invariant; KSPLIT numerically forbidden; reg-dbuf spills;
// unroll neutral; COPT scans complete; occupancy grid-capped by bit-exact
// wave-count arithmetic). Budget audit: conv2/3/4+tail+gaps ~260 of 358us;
// largest unmeasured piece is conv1: R15 doubled z to 8 co-groups (8x
// redundant 13KB tile staging) without isolation, and staging is SCALAR
// 33-wide rows (Common-mistake #2). This round, bit-exact conv1 fixes:
//   (1) z 8->4, 16 co/block == the R12-VERIFIED config (fmaf chain
//       byte-identical; staging redundancy halves),
//   (2) float2 staging (16 pairs + 1 scalar per row; same values, interior
//       pairs provably in-bounds: ix+1 <= 511).
// Everything else untouched. If total stays ~355-360, conv1 was small and
// all components are bounded -> measured latency floor under the numerics
// constraint; declare next round.
// ============================================================================

// ---------------- fused: weight repack (blocks 0..3968) + conv1 (rest) -------
__global__ __launch_bounds__(256) void k_pre(
    const float* __restrict__ x, const float* __restrict__ w1,
    const float* __restrict__ b1, float* __restrict__ h1,
    const float* __restrict__ w2, const float* __restrict__ w3,
    const float* __restrict__ w4, const float* __restrict__ regw,
    const float* __restrict__ clsw, float* __restrict__ wr2,
    float* __restrict__ wr3, float* __restrict__ wr4, float* __restrict__ wh) {
  __shared__ float in_t[3][33][33];
  if (blockIdx.x < 3969) {  // ---- repack (exact R19 k_repack_all body) ----
    int idx = blockIdx.x * 256 + threadIdx.x;
    if (idx < 73728) {  // conv2: CIN=64 COUT=128
      int co = idx % 128, r = idx / 128, ci = r / 9, tap = r % 9;
      wr2[idx] = w2[(co * 64 + ci) * 9 + tap];
    } else if (idx < 73728 + 294912) {  // conv3: CIN=128 COUT=256
      int i = idx - 73728;
      int co = i % 256, r = i / 256, ci = r / 9, tap = r % 9;
      wr3[i] = w3[(co * 128 + ci) * 9 + tap];
    } else if (idx < 73728 + 294912 + 589824) {  // conv4: CIN=256 COUT=256
      int i = idx - (73728 + 294912);
      int co = i % 256, r = i / 256, ci = r / 9, tap = r % 9;
      wr4[i] = w4[(co * 256 + ci) * 9 + tap];
    } else if (idx < 73728 + 294912 + 589824 + 57600) {  // head
      int i = idx - (73728 + 294912 + 589824);
      int ci = i & 255, r = i >> 8, tap = r / 25, o = r % 25;
      wh[i] = (o < 4) ? regw[(o * 256 + ci) * 9 + tap]
                      : clsw[((o - 4) * 256 + ci) * 9 + tap];
    }
    return;
  }
  // ---- conv1: 3->64, 512->256, stride 2. R12-verified z=4 (16 co/block),
  //      float2-vectorized staging (same values; interior pairs in-bounds).
  const int b = blockIdx.x - 3969;          // 0..1023
  const int tid = threadIdx.x;
  const int tx = tid & 15, ty = tid >> 4;
  const int ox0 = (b & 15) * 16, oy0 = ((b >> 4) & 15) * 16;
  const int co0 = (b >> 8) * 16;
  for (int e = tid; e < 3 * 33 * 17; e += 256) {
    int ci = e / 561, rem = e % 561;
    int r = rem / 17, p = rem % 17;
    int iy = oy0 * 2 + r, ix = ox0 * 2 + 2 * p;
    float v0 = 0.f, v1 = 0.f;
    if (iy < 512) {
      if (p < 16) {  // ix+1 = ox0*2+2p+1 <= 480+31 = 511 < 512, always ok
        float2 t = *(const float2*)(x + (size_t)ci * 262144 + iy * 512 + ix);
        v0 = t.x; v1 = t.y;
      } else if (ix < 512) {
        v0 = x[(size_t)ci * 262144 + iy * 512 + ix];
      }
    }
    in_t[ci][r][2 * p] = v0;
    if (p < 16) in_t[ci][r][2 * p + 1] = v1;
  }
  __syncthreads();
  float rin[27];
#pragma unroll
  for (int ci = 0; ci < 3; ++ci)
#pragma unroll
    for (int kh = 0; kh < 3; ++kh)
#pragma unroll
      for (int kw = 0; kw < 3; ++kw)
        rin[ci * 9 + kh * 3 + kw] = in_t[ci][2 * ty + kh][2 * tx + kw];
  const int oy = oy0 + ty, ox = ox0 + tx;
  for (int co = co0; co < co0 + 16; ++co) {  // co uniform -> weights via s_load
    float a = 0.f;
#pragma unroll
    for (int k = 0; k < 27; ++k) a = fmaf(w1[co * 27 + k], rin[k], a);
    h1[(size_t)co * 65536 + oy * 256 + ox] = fmaxf(a + b1[co], 0.f);
  }
}

// ---------------- generic stride-2 3x3 conv, SAME(pad lo 0 hi 1) -------------
// NW waves = NW co-groups (wave-uniform cout) x 64 lanes.
// Lane lp -> output position (py=lp/SW, px=lp%SW); SH*SW == 64.
// Input LDS row: [EV: SW+1 even cols | OD: SW odd cols | pad] = ROWW words.
// WLDS=1: weights double-buffered in LDS via global_load_lds (no VGPRs);
//         compute reads wave-uniform ds_read_b128 broadcast.
// WLDS=0: weights via wave-uniform s_load from global.
// Per-output accumulation order: tap 0..8 = (kh,kw) lexicographic, ci asc
// — bit-identical to R12 in all paths.
template <int CIN, int COUT, int HIN, int WIN, int SH, int SW, int COPT,
          int CIT, int KSPLIT, int ROWW, int NW, int WLDS>
__global__ __launch_bounds__(NW * 64, 4) void conv_s2(
    const float* __restrict__ in, const float* __restrict__ wr,
    const float* __restrict__ bias, float* __restrict__ out) {
  constexpr int HOUT = HIN / 2, WOUT = WIN / 2;
  constexpr int IH = SH * 2 + 1, IW = SW * 2 + 1;
  constexpr int EVW = SW + 1;
  constexpr int COT = NW * COPT;
  constexpr int NPAIR = CIT * IH * EVW;
  constexpr int NTHR = NW * 64;
  constexpr int NLD = (NPAIR + NTHR - 1) / NTHR;
  constexpr int NC4 = COPT / 4;          // float4 chunks per wave per tap
  constexpr int CO4 = COT / 4;           // float4 cols per weight slab row
  constexpr int W4  = CIT * 9 * CO4;     // float4s in per-stage weight slab
  static_assert(SH * SW == 64, "one position per lane");
  static_assert(EVW + SW < ROWW + 1, "pad slot fits");
  static_assert(COPT % 4 == 0, "float4 weight chunks");
  static_assert(!WLDS || (W4 % 64 == 0), "whole lane-rounds");
  __shared__ float lds[CIT * IH * ROWW];
  __shared__ float4 wlds4[WLDS == 1 ? 2 * W4 : (WLDS ? W4 : 1)];

  const int tid = threadIdx.x;
  const int gu  = __builtin_amdgcn_readfirstlane(tid >> 6);
  const int lp  = tid & 63;
  const int py  = lp / SW, px = lp % SW;

  constexpr int ntx = WOUT / SW;
  const int bx = blockIdx.x % ntx, by = blockIdx.x / ntx;
  const int ox0 = bx * SW, oy0 = by * SH;
  const int co_blk = blockIdx.y * COT;
  const int cobase = co_blk + gu * COPT;
  const int ci_begin = (KSPLIT > 1) ? blockIdx.z * (CIN / KSPLIT) : 0;
  constexpr int NST = (CIN / KSPLIT) / CIT;

  // ---- weight slab loader: global -> LDS direct, no VGPR round-trip ----
  auto wload = [&](int cibN, int bsel) {
#pragma unroll
    for (int r = 0; r < W4 / 64; ++r) {
      if ((r & (NW - 1)) == gu) {          // wave-uniform round split
        int f4 = r * 64 + lp;
        int row = f4 / CO4, c4 = f4 % CO4; // row = ci*9+tap within stage
        const float* g =
            wr + (size_t)(cibN * 9 + row) * COUT + co_blk + c4 * 4;
        __builtin_amdgcn_global_load_lds(
            (const __attribute__((address_space(1))) void*)g,
            (__attribute__((address_space(3))) void*)&wlds4[bsel * W4 + r * 64],
            16, 0, 0);
      }
    }
  };

  // ---- stage-invariant INPUT staging descriptors (advance by channel) ----
  unsigned goff[NLD];  // float offset of even element
  int      loff[NLD];  // LDS even-slot word offset; -1 if idx >= NPAIR
  int      mode[NLD];  // 0 = zero-fill, 1 = float2 pair, 2 = single even col
#pragma unroll
  for (int j = 0; j < NLD; ++j) {
    int idx = tid + j * NTHR;
    bool act = (idx < NPAIR);
    int ci = idx / (IH * EVW), rem = idx % (IH * EVW);
    int r = rem / EVW, c2 = rem % EVW;
    int iy = oy0 * 2 + r, ix = ox0 * 2 + 2 * c2;
    loff[j] = act ? (ci * IH + r) * ROWW + c2 : -1;
    goff[j] = (unsigned)((ci_begin + ci) * HIN * WIN + iy * WIN + ix);
    int m = 0;
    if (act && iy < HIN) {
      if ((2 * c2 + 1 < IW) && (ix + 1 < WIN)) m = 1;
      else if (ix < WIN) m = 2;
    }
    mode[j] = m;
  }

  // ---- prologue: issue stage-0 weight slab + prefetch stage-0 inputs ----
  if constexpr (WLDS) wload(ci_begin, 0);
  float2 pre[NLD];
#pragma unroll
  for (int j = 0; j < NLD; ++j) {
    float2 t = make_float2(0.f, 0.f);
    if (mode[j] == 1)      t = *(const float2*)(in + goff[j]);
    else if (mode[j] == 2) t.x = in[goff[j]];
    pre[j] = t;
  }

  float acc[COPT] = {};

  constexpr unsigned IADV = (unsigned)(CIT * HIN * WIN);
  unsigned iadv = IADV;
  for (int st = 0; st < NST; ++st, iadv += IADV) {
    const int cib = ci_begin + st * CIT;
    if (st) {
      __syncthreads();   // previous stage's compute reads done (slab free)
      if constexpr (WLDS == 2) wload(cib, 0);  // single-buffer slab load
    }
    // ---- write prefetched stage st inputs to LDS (same slots as R12) ----
#pragma unroll
    for (int j = 0; j < NLD; ++j) {
      if (loff[j] >= 0) {
        lds[loff[j]] = pre[j].x;        // even col c2
        lds[loff[j] + EVW] = pre[j].y;  // odd col c2 (c2==SW -> pad slot)
      }
    }
    __syncthreads();  // hipcc drains vmcnt(0) here -> weight slab st ready
    // ---- issue stage st+1's loads AFTER the barrier: drained at the NEXT
    //      stage's barriers, i.e. hidden under the compute phase below ----
    if (st + 1 < NST) {
      if constexpr (WLDS == 1) wload(cib + CIT, (st + 1) & 1);
#pragma unroll
      for (int j = 0; j < NLD; ++j) {
        float2 t = make_float2(0.f, 0.f);
        if (mode[j] == 1)      t = *(const float2*)(in + goff[j] + iadv);
        else if (mode[j] == 2) t.x = in[goff[j] + iadv];
        pre[j] = t;
      }
    }
    // ---- compute: 9 taps per ci; inputs from LDS; weights per WLDS ----
#pragma unroll 2
    for (int ci = 0; ci < CIT; ++ci) {
      const int b0 = (ci * IH + 2 * py) * ROWW + px;
      float in9[9];
      in9[0] = lds[b0];                    // (kh0,kw0) col 2px
      in9[1] = lds[b0 + EVW];              // (kh0,kw1) col 2px+1
      in9[2] = lds[b0 + 1];                // (kh0,kw2) col 2px+2
      in9[3] = lds[b0 + ROWW];
      in9[4] = lds[b0 + ROWW + EVW];
      in9[5] = lds[b0 + ROWW + 1];
      in9[6] = lds[b0 + 2 * ROWW];
      in9[7] = lds[b0 + 2 * ROWW + EVW];
      in9[8] = lds[b0 + 2 * ROWW + 1];
      if constexpr (WLDS) {
        const float4* wb = (WLDS == 1) ? &wlds4[(st & 1) * W4] : &wlds4[0];
        const int wrow = ci * 9 * CO4 + gu * NC4;
#pragma unroll
        for (int t = 0; t < 9; ++t) {
#pragma unroll
          for (int q = 0; q < NC4; ++q) {
            float4 wv = wb[wrow + t * CO4 + q];
            acc[q * 4 + 0] = fmaf(in9[t], wv.x, acc[q * 4 + 0]);
            acc[q * 4 + 1] = fmaf(in9[t], wv.y, acc[q * 4 + 1]);
            acc[q * 4 + 2] = fmaf(in9[t], wv.z, acc[q * 4 + 2]);
            acc[q * 4 + 3] = fmaf(in9[t], wv.w, acc[q * 4 + 3]);
          }
        }
      } else {
        const float* wp = wr + (size_t)(cib + ci) * 9 * COUT + cobase;
#pragma unroll
        for (int t = 0; t < 9; ++t)
#pragma unroll
          for (int c = 0; c < COPT; ++c)
            acc[c] = fmaf(in9[t], wp[t * COUT + c], acc[c]);
      }
    }
  }

  const int oy = oy0 + py, ox = ox0 + px;
#pragma unroll
  for (int c = 0; c < COPT; ++c) {
    int co = cobase + c;
    if constexpr (KSPLIT > 1) {
      out[((size_t)blockIdx.z * COUT + co) * (HOUT * WOUT) + oy * WOUT + ox] =
          acc[c];
    } else {
      out[(size_t)co * (HOUT * WOUT) + oy * WOUT + ox] =
          fmaxf(acc[c] + bias[co], 0.f);
    }
  }
}

// ---------------- combine conv4 K-split partials + bias + relu, write NHWC ---
// EXACT R0 semantics: v = ((p0+p1)+p2)+p3; out = max(v+b, 0)
__global__ __launch_bounds__(256) void k_combine(const float* __restrict__ part,
                                                 const float* __restrict__ b,
                                                 float* __restrict__ h4t) {
  int co = blockIdx.x;  // 0..255
  float bb = b[co];
  for (int k2 = 0; k2 < 4; ++k2) {
    int pos = threadIdx.x + k2 * 256;
    float v = part[(size_t)(0 * 256 + co) * 1024 + pos] +
              part[(size_t)(1 * 256 + co) * 1024 + pos] +
              part[(size_t)(2 * 256 + co) * 1024 + pos] +
              part[(size_t)(3 * 256 + co) * 1024 + pos];
    h4t[(size_t)pos * 256 + co] = fmaxf(v + bb, 0.f);
  }
}

// ---------------- head: reg(4)+cls(21) stride-1 conv + softmax/max/argmax ----
__global__ __launch_bounds__(256) void k_head(const float* __restrict__ h4t,
                                              const float* __restrict__ wh,
                                              const float* __restrict__ regb,
                                              const float* __restrict__ clsb,
                                              float* __restrict__ locs,
                                              float* __restrict__ confs,
                                              float* __restrict__ scores,
                                              float* __restrict__ labelsF) {
  const int pos = blockIdx.x;
  const int py = pos >> 5, px = pos & 31;
  const int t = threadIdx.x;
  float part[25] = {};
#pragma unroll
  for (int kh = 0; kh < 3; ++kh) {
    int iy = py + kh - 1;
    if (iy < 0 || iy > 31) continue;  // block-uniform
#pragma unroll
    for (int kw = 0; kw < 3; ++kw) {
      int ix = px + kw - 1;
      if (ix < 0 || ix > 31) continue;
      int tap = kh * 3 + kw;
      float v = h4t[(size_t)(iy * 32 + ix) * 256 + t];
      const float* wp = wh + (size_t)tap * 25 * 256 + t;
#pragma unroll
      for (int o = 0; o < 25; ++o)
        part[o] = fmaf(v, wp[(size_t)o * 256], part[o]);
    }
  }
#pragma unroll
  for (int o = 0; o < 25; ++o) {
#pragma unroll
    for (int d = 1; d < 64; d <<= 1) part[o] += __shfl_xor(part[o], d);
  }
  __shared__ float red[4][25];
  __shared__ float yv[25];
  const int wv = t >> 6, ln = t & 63;
  if (ln == 0) {
#pragma unroll
    for (int o = 0; o < 25; ++o) red[wv][o] = part[o];
  }
  __syncthreads();
  if (t < 25) {
    float y = red[0][t] + red[1][t] + red[2][t] + red[3][t];
    y += (t < 4) ? regb[t] : clsb[t - 4];
    if (t < 4) locs[(size_t)pos * 4 + t] = y;
    else       confs[(size_t)pos * 21 + (t - 4)] = y;
    yv[t] = y;
  }
  __syncthreads();
  if (t == 0) {
    float m = yv[4];
    int lab = 0;
    for (int j = 1; j < 21; ++j)
      if (yv[4 + j] > m) { m = yv[4 + j]; lab = j; }  // first-max semantics
    float s = 0.f;
    for (int j = 0; j < 21; ++j) s += expf(yv[4 + j] - m);
    scores[pos] = 1.f / s;   // max softmax prob
    labelsF[pos] = (float)lab;
  }
}

// ---------------- stable descending bitonic sort of 1024 scores --------------
__global__ __launch_bounds__(512) void k_sort(const float* __restrict__ scores,
                                              const float* __restrict__ locs,
                                              int* __restrict__ order,
                                              float* __restrict__ ssc,
                                              float* __restrict__ bsrt,
                                              unsigned long long* __restrict__ vbits) {
  __shared__ float sk[1024];
  __shared__ int   si[1024];
  const int t = threadIdx.x;
  sk[t] = scores[t];           si[t] = t;
  sk[t + 512] = scores[t + 512]; si[t + 512] = t + 512;
  for (int k = 2; k <= 1024; k <<= 1) {
    for (int j = k >> 1; j > 0; j >>= 1) {
      __syncthreads();
      int i1 = ((t / j) * (2 * j)) + (t % j);
      int i2 = i1 + j;
      bool up = (i1 & k) == 0;
      float sa = sk[i1], sb = sk[i2];
      int ia = si[i1], ib = si[i2];
      bool b_before_a = (sb > sa) || (sb == sa && ib < ia);
      bool a_before_b = (sa > sb) || (sa == sb && ia < ib);
      bool sw = up ? b_before_a : a_before_b;
      if (sw) { sk[i1] = sb; sk[i2] = sa; si[i1] = ib; si[i2] = ia; }
    }
  }
  __syncthreads();
  for (int i = t; i < 1024; i += 512) {
    int oi = si[i];
    order[i] = oi;
    ssc[i] = sk[i];
    ((float4*)bsrt)[i] = ((const float4*)locs)[oi];
  }
  if (t < 16) {  // validity bits (score > SCORE_THR), sorted order
    unsigned long long w = 0;
    for (int b2 = 0; b2 < 64; ++b2)
      if (sk[t * 64 + b2] > 0.04f) w |= (1ull << b2);
    vbits[t] = w;
  }
}

// ---------------- pairwise IoU suppression bitmask (1024x1024 bits) ----------
__global__ __launch_bounds__(256) void k_mask(const float* __restrict__ bsrt,
                                              unsigned long long* __restrict__ mask) {
  __shared__ float4 sb[1024];
  const int t = threadIdx.x;
  for (int idx = t; idx < 1024; idx += 256)
    sb[idx] = ((const float4*)bsrt)[idx];
  __syncthreads();
  const int i = blockIdx.x * 16 + (t & 15);
  const int w = t >> 4;
  float4 bi = sb[i];
  float ai = (bi.z - bi.x) * (bi.w - bi.y);
  unsigned long long bits = 0;
  for (int jj = 0; jj < 64; ++jj) {
    float4 bj = sb[w * 64 + jj];
    float aj = (bj.z - bj.x) * (bj.w - bj.y);
    float ltx = fmaxf(bi.x, bj.x), lty = fmaxf(bi.y, bj.y);
    float rbx = fminf(bi.z, bj.z), rby = fminf(bi.w, bj.w);
    float inter = fmaxf(rbx - ltx, 0.f) * fmaxf(rby - lty, 0.f);
    float uni = ai + aj - inter;
    float iou = inter / (uni + 1e-9f);
    if (iou > 0.5f) bits |= (1ull << jj);
  }
  mask[(size_t)i * 16 + w] = bits;
}

// ---------------- parallel fixpoint greedy NMS + fused gather ----------------
__global__ __launch_bounds__(1024) void k_nms_gather(
    const unsigned long long* __restrict__ mask,
    const unsigned long long* __restrict__ vbits,
    const int* __restrict__ order, const float* __restrict__ ssc,
    const float* __restrict__ locs, const float* __restrict__ confs,
    const float* __restrict__ labelsF, float* __restrict__ out) {
  __shared__ unsigned long long KEEP[16], DEAD[16];
  __shared__ int ncert;
  const int i = threadIdx.x;        // box index (sorted order)
  const int w = i >> 6, l = i & 63; // wave, lane

  unsigned long long R[16];
#pragma unroll
  for (int k = 0; k < 16; ++k) {
    unsigned long long m = 0;
    if (k < w) m = mask[(size_t)i * 16 + k];
    else if (k == w && l) m = mask[(size_t)i * 16 + k] & ((1ull << l) - 1ull);
    R[k] = m;
  }
  const bool valid = (vbits[w] >> l) & 1ull;

  if (i < 16) { KEEP[i] = 0ull; DEAD[i] = 0ull; }
  if (i == 0) ncert = 0;
  __syncthreads();

  int status = 0;  // 0 unknown, 1 kept, 2 dead
  for (;;) {
    unsigned long long s = 0, p = 0;
    if (status == 0) {
#pragma unroll
      for (int k = 0; k < 16; ++k) {
        unsigned long long K_ = KEEP[k], D_ = DEAD[k];
        s |= R[k] & K_;
        p |= R[k] & ~D_;
      }
    }
    __syncthreads();  // all reads done before any write
    bool newKeep = false, newDead = false;
    if (status == 0) {
      if (!valid)      { status = 2; newDead = true; }
      else if (s)      { status = 2; newDead = true; }
      else if (!p)     { status = 1; newKeep = true; }
    }
    unsigned long long bk = __ballot(newKeep);
    unsigned long long bd = __ballot(newDead);
    if (l == 0) {
      if (bk) KEEP[w] |= bk;
      if (bd) DEAD[w] |= bd;
      int n = __popcll(bk) + __popcll(bd);
      if (n) atomicAdd(&ncert, n);
    }
    __syncthreads();
    if (ncert >= 1024) break;
  }

  const bool kp = (status == 1);
  const int oi = order[i];
  float4 bx = kp ? ((const float4*)locs)[oi]
                 : make_float4(-1.f, -1.f, -1.f, -1.f);
  ((float4*)out)[i] = bx;
  out[4096 + i] = kp ? labelsF[oi] : 0.f;
  out[5120 + i] = kp ? ssc[i] : -1.f;
  float* oc = out + 6144 + (size_t)i * 21;
  const float* cc = confs + (size_t)oi * 21;
#pragma unroll
  for (int c = 0; c < 21; ++c) oc[c] = kp ? cc[c] : -1.f;
}

// ============================================================================
extern "C" void kernel_launch(void* const* d_in, const int* in_sizes, int n_in,
                              void* d_out, int out_size, void* d_ws, size_t ws_size,
                              hipStream_t stream) {
  const float* x    = (const float*)d_in[0] + (size_t)7 * 3 * 512 * 512;  // image 7
  const float* w1   = (const float*)d_in[1];
  const float* b1   = (const float*)d_in[2];
  const float* w2   = (const float*)d_in[3];
  const float* b2   = (const float*)d_in[4];
  const float* w3   = (const float*)d_in[5];
  const float* b3   = (const float*)d_in[6];
  const float* w4   = (const float*)d_in[7];
  const float* b4   = (const float*)d_in[8];
  const float* regw = (const float*)d_in[9];
  const float* regb = (const float*)d_in[10];
  const float* clsw = (const float*)d_in[11];
  const float* clsb = (const float*)d_in[12];
  float* out = (float*)d_out;
  char* ws = (char*)d_ws;

  // region A (0..16.8MB): h1, then part4 + h4t   (R12 layout)
  float* h1    = (float*)(ws + 0);          // 16.8MB  (dead after conv2)
  float* part4 = (float*)(ws + 0);          // 4MB     (dead after combine)
  float* h4t   = (float*)(ws + 9437184);    // 1MB
  float* h2    = (float*)(ws + 16777216);   // 8.4MB   (dead after conv3)
  float* h3    = (float*)(ws + 25165824);   // 4.2MB
  float* wr2   = (float*)(ws + 29360128);
  float* wr3   = (float*)(ws + 29655040);
  float* wr4   = (float*)(ws + 30834688);
  float* wh    = (float*)(ws + 33193984);
  float* locs  = (float*)(ws + 33424384);
  float* confs = (float*)(ws + 33440768);
  float* scores  = (float*)(ws + 33526784);
  float* labelsF = (float*)(ws + 33530880);
  int*   order   = (int*)  (ws + 33534976);
  float* ssc     = (float*)(ws + 33539072);
  float* bsrt    = (float*)(ws + 33543168);
  unsigned long long* mask  = (unsigned long long*)(ws + 33559552);
  unsigned long long* vbits = (unsigned long long*)(ws + 33690624);

  // fused repack (3969 blocks) + conv1 z=4 (1024 blocks)
  k_pre<<<4993, 256, 0, stream>>>(x, w1, b1, h1, w2, w3, w4, regw, clsw,
                                  wr2, wr3, wr4, wh);

  // conv2: COPT=8, 256 sp x 4 co = 1024 blocks, ROWW=36, s_load path (R19)
  conv_s2<64, 128, 256, 256, 4, 16, 8, 16, 1, 36, 4, 0>
      <<<dim3(256, 4, 1), 256, 0, stream>>>(h1, wr2, b2, h2);
  // conv3: COPT=4, 64 sp x 16 co = 1024 blocks, ROWW=20, weight-LDS dbuf
  conv_s2<128, 256, 128, 128, 8, 8, 4, 16, 1, 20, 4, 1>
      <<<dim3(64, 16, 1), 256, 0, stream>>>(h2, wr3, b3, h3);
  // conv4: COPT=4, KSPLIT=4, 1024 blocks, weight-LDS dbuf (R19)
  conv_s2<256, 256, 64, 64, 8, 8, 4, 16, 4, 20, 4, 1>
      <<<dim3(16, 16, 4), 256, 0, stream>>>(h3, wr4, (const float*)nullptr, part4);
  k_combine<<<256, 256, 0, stream>>>(part4, b4, h4t);

  k_head<<<1024, 256, 0, stream>>>(h4t, wh, regb, clsb, locs, confs, scores, labelsF);

  k_sort<<<1, 512, 0, stream>>>(scores, locs, order, ssc, bsrt, vbits);
  k_mask<<<64, 256, 0, stream>>>(bsrt, mask);
  k_nms_gather<<<1, 1024, 0, stream>>>(mask, vbits, order, ssc, locs, confs,
                                       labelsF, out);
}